// Round 4
// baseline (423.477 us; speedup 1.0000x reference)
//
#include <hip/hip_runtime.h>
#include <cmath>

#ifndef __has_builtin
#define __has_builtin(x) 0
#endif

#define B_DIM 4096
#define K_DIM 2048
#define N_DIM 2048

#define BM 128
#define BN 64
#define BK 128   // fp8 elements per K-tile (one 16x16x128 MFMA step)

typedef __attribute__((ext_vector_type(4))) float f32x4;
typedef __attribute__((ext_vector_type(8))) int   v8i;
typedef __attribute__((ext_vector_type(4))) int   i32x4;

// ---------- helpers ----------

__device__ __forceinline__ void gl2lds16(const void* g, void* l) {
#if __has_builtin(__builtin_amdgcn_global_load_lds)
    __builtin_amdgcn_global_load_lds((__attribute__((address_space(1))) void*)g,
                                     (__attribute__((address_space(3))) void*)l,
                                     16, 0, 0);
#else
    *(uint4*)l = *(const uint4*)g;
#endif
}

// ---------- prep: fp32 -> fp8 e4m3 casts ----------
// X in {0,1}, rint(W) small ints: exact in e4m3 (ints <= 16 exact); fp32 MFMA
// accumulation of <=2048 such terms is exact -> results identical to fp32 ref.

__global__ void cast_x_kernel(const float* __restrict__ X,
                              unsigned char* __restrict__ Xb) {
    size_t i = ((size_t)blockIdx.x * 256 + threadIdx.x) * 8;
    f32x4 a = *(const f32x4*)(X + i);
    f32x4 b = *(const f32x4*)(X + i + 4);
    int lo = __builtin_amdgcn_cvt_pk_fp8_f32(a[0], a[1], 0, false);
    lo     = __builtin_amdgcn_cvt_pk_fp8_f32(a[2], a[3], lo, true);
    int hi = __builtin_amdgcn_cvt_pk_fp8_f32(b[0], b[1], 0, false);
    hi     = __builtin_amdgcn_cvt_pk_fp8_f32(b[2], b[3], hi, true);
    int2 o; o.x = lo; o.y = hi;
    *(int2*)(Xb + i) = o;
}

__global__ void cast_w_kernel(const float* __restrict__ Wa,
                              const float* __restrict__ Ws,
                              unsigned char* __restrict__ Wab,
                              unsigned char* __restrict__ Wsb) {
    size_t i = ((size_t)blockIdx.x * 256 + threadIdx.x) * 8;
    f32x4 a0 = *(const f32x4*)(Wa + i);
    f32x4 a1 = *(const f32x4*)(Wa + i + 4);
    f32x4 s0 = *(const f32x4*)(Ws + i);
    f32x4 s1 = *(const f32x4*)(Ws + i + 4);
    int lo = __builtin_amdgcn_cvt_pk_fp8_f32(rintf(a0[0]), rintf(a0[1]), 0, false);
    lo     = __builtin_amdgcn_cvt_pk_fp8_f32(rintf(a0[2]), rintf(a0[3]), lo, true);
    int hi = __builtin_amdgcn_cvt_pk_fp8_f32(rintf(a1[0]), rintf(a1[1]), 0, false);
    hi     = __builtin_amdgcn_cvt_pk_fp8_f32(rintf(a1[2]), rintf(a1[3]), hi, true);
    int2 oa; oa.x = lo; oa.y = hi;
    lo = __builtin_amdgcn_cvt_pk_fp8_f32(rintf(s0[0]), rintf(s0[1]), 0, false);
    lo = __builtin_amdgcn_cvt_pk_fp8_f32(rintf(s0[2]), rintf(s0[3]), lo, true);
    hi = __builtin_amdgcn_cvt_pk_fp8_f32(rintf(s1[0]), rintf(s1[1]), 0, false);
    hi = __builtin_amdgcn_cvt_pk_fp8_f32(rintf(s1[2]), rintf(s1[3]), hi, true);
    int2 os; os.x = lo; os.y = hi;
    *(int2*)(Wab + i) = oa;
    *(int2*)(Wsb + i) = os;
}

// ---------- fused dual-GEMM (MX-fp8 K=128) + DPI neuron update ----------
// 128x64 tile, BK=128 fp8, 4 waves 2x2 (wm in {0,64}, wn in {0,32}); each wave
// 64x32 via 4x2 mfma_scale_f32_16x16x128_f8f6f4 (scales = 1.0) per GEMM.
// 32KB LDS -> 4 blocks/CU. XOR chunk swizzle keeps ds_read_b128 conflict-free.
// Epilogue transposes through LDS so all global I/O is row-contiguous float4.

#define RS 68    // LDS float row stride for epilogue (64 + 4 pad)

// assemble a 32B fragment (logical chunks q2,q2+1 of `row`) from swizzled LDS
__device__ __forceinline__ v8i load_frag(const unsigned char* base, int row,
                                         int q2, int swzr) {
    union { i32x4 h[2]; v8i v; } u;
    const unsigned char* r = base + row * BK;
    u.h[0] = *(const i32x4*)(r + (((q2    ) ^ swzr) << 4));
    u.h[1] = *(const i32x4*)(r + (((q2 + 1) ^ swzr) << 4));
    return u.v;
}

__global__ __launch_bounds__(256, 4)
void dpi_fused_kernel(const unsigned char* __restrict__ Xb,
                      const unsigned char* __restrict__ Wab,
                      const unsigned char* __restrict__ Wsb,
                      const float* __restrict__ gImem,
                      const float* __restrict__ gIampa,
                      const float* __restrict__ gIshunt,
                      const float* __restrict__ gRefr,
                      const float* __restrict__ pIdc,
                      const float* __restrict__ pIwa,
                      const float* __restrict__ pIws,
                      const float* __restrict__ pAlpha,
                      const float* __restrict__ pBeta,
                      float* __restrict__ out,
                      float i0pow, float kexp, float tau_mem, float inv_tau_syn)
{
    __shared__ __align__(16) unsigned char smem[32768];
    unsigned char* sA  = smem;            // 128 x 128B = 16 KB
    unsigned char* sWa = smem + 16384;    //  64 x 128B =  8 KB
    unsigned char* sWs = smem + 24576;    //  8 KB
    float* na_buf = (float*)smem;         // 32*RS*4 = 8704 B
    float* ns_buf = (float*)(smem + 8704);

    const int tid  = threadIdx.x;
    const int lane = tid & 63;
    const int wave = tid >> 6;

    // XCD-aware swizzle: 8 XCDs, each owns an 8(m) x 16(n) block region
    const int lin = blockIdx.x;                  // 0..1023
    const int xcd = lin & 7;
    const int loc = lin >> 3;                    // 0..127
    const int mb  = (xcd & 3) * 8 + (loc & 7);   // 0..31
    const int nb  = (xcd >> 2) * 16 + (loc >> 3);// 0..31
    const int m0  = mb * BM;
    const int n0  = nb * BN;

    const int wm = (wave & 1) * 64;
    const int wn = (wave >> 1) * 32;

    f32x4 accA[4][2], accS[4][2];
#pragma unroll
    for (int i = 0; i < 4; i++)
#pragma unroll
        for (int j = 0; j < 2; j++) { accA[i][j] = (f32x4)0.0f; accS[i][j] = (f32x4)0.0f; }

    const int frow = lane & 15;           // m (or n) within a 16-frag
    const int q2   = (lane >> 4) * 2;     // first 16B chunk of this lane's 32B k-slice
    const int swzr = frow & 7;            // XOR swizzle row component

    for (int k0 = 0; k0 < K_DIM; k0 += BK) {
        // stage A (1024 x 16B chunks) + Wa/Ws (512 each). LDS dst is forced
        // contiguous (base + lane*16); XOR-swizzle the GLOBAL source chunk so
        // row r's chunk j lands at slot j^(r&7).
#pragma unroll
        for (int j = 0; j < 4; j++) {
            int c    = j * 256 + tid;
            int row  = c >> 3;
            int jsrc = (c & 7) ^ (row & 7);
            gl2lds16(Xb + (size_t)(m0 + row) * K_DIM + k0 + jsrc * 16, sA + c * 16);
        }
#pragma unroll
        for (int j = 0; j < 2; j++) {
            int c    = j * 256 + tid;
            int row  = c >> 3;
            int jsrc = (c & 7) ^ (row & 7);
            size_t goffW = (size_t)(n0 + row) * K_DIM + k0 + jsrc * 16;
            gl2lds16(Wab + goffW, sWa + c * 16);
            gl2lds16(Wsb + goffW, sWs + c * 16);
        }
        __syncthreads();

        v8i af[4];
#pragma unroll
        for (int mi = 0; mi < 4; mi++)
            af[mi] = load_frag(sA, wm + mi * 16 + frow, q2, swzr);
#pragma unroll
        for (int ni = 0; ni < 2; ni++) {
            const v8i ba = load_frag(sWa, wn + ni * 16 + frow, q2, swzr);
            const v8i bs = load_frag(sWs, wn + ni * 16 + frow, q2, swzr);
#pragma unroll
            for (int mi = 0; mi < 4; mi++) {
                // fmt 0 = e4m3; scale bytes 0x7F = x1.0 (E8M0 bias 127)
                accA[mi][ni] = __builtin_amdgcn_mfma_scale_f32_16x16x128_f8f6f4(
                    af[mi], ba, accA[mi][ni], 0, 0, 0, 127, 0, 127);
                accS[mi][ni] = __builtin_amdgcn_mfma_scale_f32_16x16x128_f8f6f4(
                    af[mi], bs, accS[mi][ni], 0, 0, 0, 127, 0, 127);
            }
        }
        __syncthreads();
    }

    // ---- epilogue: transpose through LDS, then contiguous float4 I/O ----
    const float idc   = *pIdc;
    const float iwa   = *pIwa;
    const float iws   = *pIws;
    const float alpha = *pAlpha;
    const float beta  = *pBeta;

    const size_t plane = (size_t)B_DIM * N_DIM;
    float* __restrict__ oSpike = out;
    float* __restrict__ oImem  = out + plane;
    float* __restrict__ oIampa = out + 2 * plane;
    float* __restrict__ oIsh   = out + 3 * plane;
    float* __restrict__ oRefr  = out + 4 * plane;

    const int rowgroup = wm >> 6;          // 0 or 1
    const int quad4    = (lane >> 4) << 2; // 0,4,8,12
    const int cseg     = (tid & 15) * 4;   // float4 column (0..60)
    const int rgrp     = tid >> 4;         // 0..15 -> rows rgrp*2..+1

#pragma unroll
    for (int s = 0; s < 4; s++) {          // s == mi: 32 rows of the tile per step
        // scatter fragments into LDS (C/D layout: col=lane&15, row=quad*4+r)
#pragma unroll
        for (int ni = 0; ni < 2; ni++) {
            const int lcol = wn + ni * 16 + (lane & 15);
#pragma unroll
            for (int r = 0; r < 4; r++) {
                const int lrow = rowgroup * 16 + quad4 + r;
                na_buf[lrow * RS + lcol] = accA[s][ni][r];
                ns_buf[lrow * RS + lcol] = accS[s][ni][r];
            }
        }
        __syncthreads();

        // contiguous compute + store: each thread owns 2 rows x 1 float4
#pragma unroll
        for (int q = 0; q < 2; q++) {
            const int lrow = rgrp * 2 + q;
            const int grow = m0 + (lrow >> 4) * 64 + s * 16 + (lrow & 15);
            const size_t idx = (size_t)grow * N_DIM + n0 + cseg;

            const f32x4 na4 = *(const f32x4*)(na_buf + lrow * RS + cseg);
            const f32x4 ns4 = *(const f32x4*)(ns_buf + lrow * RS + cseg);
            const f32x4 im4 = *(const f32x4*)(gImem   + idx);
            const f32x4 ia4 = *(const f32x4*)(gIampa  + idx);
            const f32x4 is4 = *(const f32x4*)(gIshunt + idx);
            const f32x4 rf4 = *(const f32x4*)(gRefr   + idx);

            f32x4 sp_o, im_o, ia_o, is_o, rf_o;
#pragma unroll
            for (int e = 0; e < 4; e++) {
                const float na  = na4[e];
                const float ns  = ns4[e];
                const float im  = im4[e];
                const float ia  = ia4[e];
                const float ish = is4[e];
                const float rf  = rf4[e];

                const float dIampa  = -ia * inv_tau_syn;
                const float ia2     = ia + iwa * na;        // IGAIN_AMPA/ITAU_AMPA = 1
                const float dIshunt = -ish * inv_tau_syn;   // TAU_SHUNT == TAU_AMPA
                const float ish2    = ish + iws * ns;

                float Iin = idc + ia2 + 5e-13f - ish2;      // Inmda = I0
                Iin = (rf <= 0.0f) ? Iin : 0.0f;
                Iin = fmaxf(Iin, 5e-13f);

                // 1+exp(-1e-12*(im-1e-12)): |arg| < 1e-21 -> exp == 1.0f exactly
                // in fp32, denominator == 2.0f. powf via v_log/v_exp.
                const float ifb = i0pow *
                    __builtin_amdgcn_exp2f(kexp * __builtin_amdgcn_logf(im)) * 0.5f;
                const float fimem = ifb * 1e12f * (im + 1e-12f);
                const float dImem = (alpha * ((Iin - 1e-12f) - 5e-13f) - beta * im + fimem)
                                    / (tau_mem * (1.0f + 1e-12f / im));
                float im2 = fmaxf(im + dImem * 0.001f, 5e-13f);

                float ia3 = fmaxf(ia2 + dIampa * 0.001f, 5e-13f);
                ia3       = fmaxf(ia3 + dIshunt * 0.001f, 5e-13f);  // faithful to ref bug

                const float spike = (im2 - 1e-12f > 0.0f) ? 1.0f : 0.0f;
                im2 = (spike > 0.0f) ? 5e-13f : im2;
                float rf2 = fmaxf(rf - 0.001f, 0.0f);
                rf2 = (spike > 0.0f) ? 0.0f : rf2;          // REFP = 0

                sp_o[e] = spike; im_o[e] = im2; ia_o[e] = ia3;
                is_o[e] = ish2;  rf_o[e] = rf2;
            }

            *(f32x4*)(oSpike + idx) = sp_o;
            *(f32x4*)(oImem  + idx) = im_o;
            *(f32x4*)(oIampa + idx) = ia_o;
            *(f32x4*)(oIsh   + idx) = is_o;
            *(f32x4*)(oRefr  + idx) = rf_o;
        }
        __syncthreads();
    }
}

// ---------- launch ----------

extern "C" void kernel_launch(void* const* d_in, const int* in_sizes, int n_in,
                              void* d_out, int out_size, void* d_ws, size_t ws_size,
                              hipStream_t stream) {
    (void)in_sizes; (void)n_in; (void)out_size; (void)ws_size;

    const float* X       = (const float*)d_in[0];
    const float* W_ampa  = (const float*)d_in[1];
    const float* W_shunt = (const float*)d_in[2];
    const float* Imem    = (const float*)d_in[3];
    const float* Iampa   = (const float*)d_in[4];
    const float* Ishunt  = (const float*)d_in[5];
    const float* Refr    = (const float*)d_in[6];
    const float* pIdc    = (const float*)d_in[7];
    const float* pIwa    = (const float*)d_in[8];
    const float* pIws    = (const float*)d_in[9];
    const float* pAlpha  = (const float*)d_in[10];
    const float* pBeta   = (const float*)d_in[11];

    unsigned char* Xb  = (unsigned char*)d_ws;                    // 8 MiB
    unsigned char* Wab = Xb  + (size_t)B_DIM * K_DIM;             // 4 MiB
    unsigned char* Wsb = Wab + (size_t)N_DIM * K_DIM;             // 4 MiB

    const float i0pow       = (float)std::pow(5e-13, 1.0 / 1.705);   // I0^(1/(k+1))
    const float kexp        = (float)(0.705 / 1.705);                // k/(k+1)
    const float tau_mem     = (float)(0.025 / 0.705 * 3.0);
    const float inv_tau_syn = (float)(1.0 / (0.025 / 0.705 * 2.0));

    cast_x_kernel<<<dim3((B_DIM * K_DIM) / (256 * 8)), dim3(256), 0, stream>>>(X, Xb);
    cast_w_kernel<<<dim3((N_DIM * K_DIM) / (256 * 8)), dim3(256), 0, stream>>>(
        W_ampa, W_shunt, Wab, Wsb);

    dpi_fused_kernel<<<dim3((B_DIM / BM) * (N_DIM / BN)), dim3(256), 0, stream>>>(
        Xb, Wab, Wsb, Imem, Iampa, Ishunt, Refr,
        pIdc, pIwa, pIws, pAlpha, pBeta,
        (float*)d_out, i0pow, kexp, tau_mem, inv_tau_syn);
}

// Round 5
// 407.513 us; speedup vs baseline: 1.0392x; 1.0392x over previous
//
#include <hip/hip_runtime.h>
#include <cmath>

#ifndef __has_builtin
#define __has_builtin(x) 0
#endif

#define B_DIM 4096
#define K_DIM 2048
#define N_DIM 2048

#define BM 128
#define BN 32
#define BK 64

typedef __attribute__((ext_vector_type(4))) float f32x4;
typedef __attribute__((ext_vector_type(8))) short bf16x8;
typedef __attribute__((ext_vector_type(8))) unsigned short u16x8;

// ---------- helpers ----------

__device__ __forceinline__ unsigned short f2bf(float f) {
    unsigned int u = __float_as_uint(f);
    u += 0x7fffu + ((u >> 16) & 1u);   // RNE; values here are small exact ints, no NaN
    return (unsigned short)(u >> 16);
}

__device__ __forceinline__ void gl2lds16(const void* g, void* l) {
#if __has_builtin(__builtin_amdgcn_global_load_lds)
    __builtin_amdgcn_global_load_lds((__attribute__((address_space(1))) void*)g,
                                     (__attribute__((address_space(3))) void*)l,
                                     16, 0, 0);
#else
    *(uint4*)l = *(const uint4*)g;
#endif
}

// ---------- prep: fp32 -> bf16 casts ----------

__global__ void cast_x_kernel(const float* __restrict__ X,
                              unsigned short* __restrict__ Xb) {
    size_t i = ((size_t)blockIdx.x * 256 + threadIdx.x) * 8;
    f32x4 a = *(const f32x4*)(X + i);
    f32x4 b = *(const f32x4*)(X + i + 4);
    u16x8 o;
    o[0] = f2bf(a[0]); o[1] = f2bf(a[1]); o[2] = f2bf(a[2]); o[3] = f2bf(a[3]);
    o[4] = f2bf(b[0]); o[5] = f2bf(b[1]); o[6] = f2bf(b[2]); o[7] = f2bf(b[3]);
    *(u16x8*)(Xb + i) = o;
}

__global__ void cast_w_kernel(const float* __restrict__ Wa,
                              const float* __restrict__ Ws,
                              unsigned short* __restrict__ Wab,
                              unsigned short* __restrict__ Wsb) {
    size_t i = ((size_t)blockIdx.x * 256 + threadIdx.x) * 8;
    f32x4 a0 = *(const f32x4*)(Wa + i);
    f32x4 a1 = *(const f32x4*)(Wa + i + 4);
    f32x4 s0 = *(const f32x4*)(Ws + i);
    f32x4 s1 = *(const f32x4*)(Ws + i + 4);
    u16x8 oa, os;
#pragma unroll
    for (int j = 0; j < 4; j++) {
        oa[j]     = f2bf(rintf(a0[j]));  // ste_round fwd = round-half-even
        oa[j + 4] = f2bf(rintf(a1[j]));
        os[j]     = f2bf(rintf(s0[j]));
        os[j + 4] = f2bf(rintf(s1[j]));
    }
    *(u16x8*)(Wab + i) = oa;
    *(u16x8*)(Wsb + i) = os;
}

// ---------- fused dual-GEMM + DPI neuron update ----------
// 128x32 tile, BK=64, 4 waves 2x2 (wm in {0,64}, wn in {0,16}); each wave
// 64x16 via 4x1 mfma_f32_16x16x32_bf16 per GEMM. 24KB LDS -> 6 blocks/CU
// (grid 2048 = 8/CU over time) for latency hiding. XOR-swizzled staging keeps
// ds_read_b128 conflict-free. Epilogue transposes through LDS; state loads and
// output stores are nontemporal row-contiguous float4 (keep L2 for staging).

#define RS 36    // LDS float row stride for epilogue (32 + 4 pad)

__global__ __launch_bounds__(256, 6)
void dpi_fused_kernel(const unsigned short* __restrict__ Xb,
                      const unsigned short* __restrict__ Wab,
                      const unsigned short* __restrict__ Wsb,
                      const float* __restrict__ gImem,
                      const float* __restrict__ gIampa,
                      const float* __restrict__ gIshunt,
                      const float* __restrict__ gRefr,
                      const float* __restrict__ pIdc,
                      const float* __restrict__ pIwa,
                      const float* __restrict__ pIws,
                      const float* __restrict__ pAlpha,
                      const float* __restrict__ pBeta,
                      float* __restrict__ out,
                      float i0pow, float kexp, float tau_mem, float inv_tau_syn)
{
    __shared__ __align__(16) unsigned char smem[24576];
    unsigned short* sA  = (unsigned short*)smem;             // 128x64 bf16 = 16 KB
    unsigned short* sWa = (unsigned short*)(smem + 16384);   //  32x64 bf16 =  4 KB
    unsigned short* sWs = (unsigned short*)(smem + 20480);   //  4 KB
    float* na_buf = (float*)smem;                            // 32*RS*4 = 4608 B
    float* ns_buf = (float*)(smem + 4608);                   // 4608 B

    const int tid  = threadIdx.x;
    const int lane = tid & 63;
    const int wave = tid >> 6;

    // XCD-aware swizzle: 8 XCDs, each owns an 8(m) x 32(n) block region
    const int lin = blockIdx.x;                  // 0..2047
    const int xcd = lin & 7;
    const int loc = lin >> 3;                    // 0..255
    const int mb  = (xcd & 3) * 8 + (loc & 7);   // 0..31
    const int nb  = (xcd >> 2) * 32 + (loc >> 3);// 0..63
    const int m0  = mb * BM;
    const int n0  = nb * BN;

    const int wm = (wave & 1) * 64;
    const int wn = (wave >> 1) * 16;

    f32x4 accA[4], accS[4];
#pragma unroll
    for (int i = 0; i < 4; i++) { accA[i] = (f32x4)0.0f; accS[i] = (f32x4)0.0f; }

    const int frow = lane & 15;           // m (or n) within a 16-frag
    const int kq   = lane >> 4;           // 0..3 -> k sub-offset kq*8
    const int swzr = frow & 7;            // XOR swizzle row component

    // W fragment row is K-loop invariant
    const int rB    = wn + frow;          // 0..31
    const int wbase = rB * 64;

    for (int k0 = 0; k0 < K_DIM; k0 += BK) {
        // stage A (1024 x 16B chunks, 4/thread) + Wa/Ws (256 chunks, 1/thread).
        // LDS dst is forced contiguous (base + lane*16); XOR-swizzle the
        // GLOBAL source chunk so row r's chunk j lands at slot j^(r&7).
#pragma unroll
        for (int j = 0; j < 4; j++) {
            int c    = j * 256 + tid;
            int row  = c >> 3;
            int jsrc = (c & 7) ^ (row & 7);
            gl2lds16(Xb + (size_t)(m0 + row) * K_DIM + k0 + jsrc * 8, sA + c * 8);
        }
        {
            int row  = tid >> 3;
            int jsrc = (tid & 7) ^ (row & 7);
            size_t goffW = (size_t)(n0 + row) * K_DIM + k0 + jsrc * 8;
            gl2lds16(Wab + goffW, sWa + tid * 8);
            gl2lds16(Wsb + goffW, sWs + tid * 8);
        }
        __syncthreads();

#pragma unroll
        for (int kk = 0; kk < 2; kk++) {
            const int jb = kk * 4 + kq;        // 16B chunk index of this lane's k
            const int ko = (jb ^ swzr) * 8;
            bf16x8 af[4];
#pragma unroll
            for (int mi = 0; mi < 4; mi++)
                af[mi] = *(const bf16x8*)(sA + (wm + mi * 16 + frow) * 64 + ko);
            const bf16x8 ba = *(const bf16x8*)(sWa + wbase + ko);
            const bf16x8 bs = *(const bf16x8*)(sWs + wbase + ko);
#pragma unroll
            for (int mi = 0; mi < 4; mi++) {
                accA[mi] = __builtin_amdgcn_mfma_f32_16x16x32_bf16(af[mi], ba, accA[mi], 0, 0, 0);
                accS[mi] = __builtin_amdgcn_mfma_f32_16x16x32_bf16(af[mi], bs, accS[mi], 0, 0, 0);
            }
        }
        __syncthreads();
    }

    // ---- epilogue: transpose through LDS, then contiguous nontemporal I/O ----
    const float idc   = *pIdc;
    const float iwa   = *pIwa;
    const float iws   = *pIws;
    const float alpha = *pAlpha;
    const float beta  = *pBeta;

    const size_t plane = (size_t)B_DIM * N_DIM;
    float* __restrict__ oSpike = out;
    float* __restrict__ oImem  = out + plane;
    float* __restrict__ oIampa = out + 2 * plane;
    float* __restrict__ oIsh   = out + 3 * plane;
    float* __restrict__ oRefr  = out + 4 * plane;

    const int rowgroup = wm >> 6;          // 0 or 1
    const int quad4    = (lane >> 4) << 2; // 0,4,8,12
    const int lcol     = wn + (lane & 15); // 0..31
    const int cseg     = (tid & 7) * 4;    // float4 column (0..28)
    const int trow     = tid >> 3;         // 0..31: each thread owns 1 row x 1 float4

#pragma unroll
    for (int s = 0; s < 4; s++) {          // s == mi: 32 rows of the tile per step
        // scatter fragments into LDS (C/D layout: col=lane&15, row=quad*4+r)
#pragma unroll
        for (int r = 0; r < 4; r++) {
            const int lrow = rowgroup * 16 + quad4 + r;
            na_buf[lrow * RS + lcol] = accA[s][r];
            ns_buf[lrow * RS + lcol] = accS[s][r];
        }
        __syncthreads();

        {
            const int grow = m0 + (trow >> 4) * 64 + s * 16 + (trow & 15);
            const size_t idx = (size_t)grow * N_DIM + n0 + cseg;

            const f32x4 na4 = *(const f32x4*)(na_buf + trow * RS + cseg);
            const f32x4 ns4 = *(const f32x4*)(ns_buf + trow * RS + cseg);
            const f32x4 im4 = __builtin_nontemporal_load((const f32x4*)(gImem   + idx));
            const f32x4 ia4 = __builtin_nontemporal_load((const f32x4*)(gIampa  + idx));
            const f32x4 is4 = __builtin_nontemporal_load((const f32x4*)(gIshunt + idx));
            const f32x4 rf4 = __builtin_nontemporal_load((const f32x4*)(gRefr   + idx));

            f32x4 sp_o, im_o, ia_o, is_o, rf_o;
#pragma unroll
            for (int e = 0; e < 4; e++) {
                const float na  = na4[e];
                const float ns  = ns4[e];
                const float im  = im4[e];
                const float ia  = ia4[e];
                const float ish = is4[e];
                const float rf  = rf4[e];

                const float dIampa  = -ia * inv_tau_syn;
                const float ia2     = ia + iwa * na;        // IGAIN_AMPA/ITAU_AMPA = 1
                const float dIshunt = -ish * inv_tau_syn;   // TAU_SHUNT == TAU_AMPA
                const float ish2    = ish + iws * ns;

                float Iin = idc + ia2 + 5e-13f - ish2;      // Inmda = I0
                Iin = (rf <= 0.0f) ? Iin : 0.0f;
                Iin = fmaxf(Iin, 5e-13f);

                // 1+exp(-1e-12*(im-1e-12)): |arg| < 1e-21 -> exp == 1.0f exactly
                // in fp32, denominator == 2.0f. powf via v_log/v_exp.
                const float ifb = i0pow *
                    __builtin_amdgcn_exp2f(kexp * __builtin_amdgcn_logf(im)) * 0.5f;
                const float fimem = ifb * 1e12f * (im + 1e-12f);
                const float dImem = (alpha * ((Iin - 1e-12f) - 5e-13f) - beta * im + fimem)
                                    / (tau_mem * (1.0f + 1e-12f / im));
                float im2 = fmaxf(im + dImem * 0.001f, 5e-13f);

                float ia3 = fmaxf(ia2 + dIampa * 0.001f, 5e-13f);
                ia3       = fmaxf(ia3 + dIshunt * 0.001f, 5e-13f);  // faithful to ref bug

                const float spike = (im2 - 1e-12f > 0.0f) ? 1.0f : 0.0f;
                im2 = (spike > 0.0f) ? 5e-13f : im2;
                float rf2 = fmaxf(rf - 0.001f, 0.0f);
                rf2 = (spike > 0.0f) ? 0.0f : rf2;          // REFP = 0

                sp_o[e] = spike; im_o[e] = im2; ia_o[e] = ia3;
                is_o[e] = ish2;  rf_o[e] = rf2;
            }

            __builtin_nontemporal_store(sp_o, (f32x4*)(oSpike + idx));
            __builtin_nontemporal_store(im_o, (f32x4*)(oImem  + idx));
            __builtin_nontemporal_store(ia_o, (f32x4*)(oIampa + idx));
            __builtin_nontemporal_store(is_o, (f32x4*)(oIsh   + idx));
            __builtin_nontemporal_store(rf_o, (f32x4*)(oRefr  + idx));
        }
        __syncthreads();
    }
}

// ---------- launch ----------

extern "C" void kernel_launch(void* const* d_in, const int* in_sizes, int n_in,
                              void* d_out, int out_size, void* d_ws, size_t ws_size,
                              hipStream_t stream) {
    (void)in_sizes; (void)n_in; (void)out_size; (void)ws_size;

    const float* X       = (const float*)d_in[0];
    const float* W_ampa  = (const float*)d_in[1];
    const float* W_shunt = (const float*)d_in[2];
    const float* Imem    = (const float*)d_in[3];
    const float* Iampa   = (const float*)d_in[4];
    const float* Ishunt  = (const float*)d_in[5];
    const float* Refr    = (const float*)d_in[6];
    const float* pIdc    = (const float*)d_in[7];
    const float* pIwa    = (const float*)d_in[8];
    const float* pIws    = (const float*)d_in[9];
    const float* pAlpha  = (const float*)d_in[10];
    const float* pBeta   = (const float*)d_in[11];

    unsigned short* Xb  = (unsigned short*)d_ws;                 // 16 MiB
    unsigned short* Wab = Xb  + (size_t)B_DIM * K_DIM;           // 8 MiB
    unsigned short* Wsb = Wab + (size_t)N_DIM * K_DIM;           // 8 MiB

    const float i0pow       = (float)std::pow(5e-13, 1.0 / 1.705);   // I0^(1/(k+1))
    const float kexp        = (float)(0.705 / 1.705);                // k/(k+1)
    const float tau_mem     = (float)(0.025 / 0.705 * 3.0);
    const float inv_tau_syn = (float)(1.0 / (0.025 / 0.705 * 2.0));

    cast_x_kernel<<<dim3((B_DIM * K_DIM) / (256 * 8)), dim3(256), 0, stream>>>(X, Xb);
    cast_w_kernel<<<dim3((N_DIM * K_DIM) / (256 * 8)), dim3(256), 0, stream>>>(
        W_ampa, W_shunt, Wab, Wsb);

    dpi_fused_kernel<<<dim3((B_DIM / BM) * (N_DIM / BN)), dim3(256), 0, stream>>>(
        Xb, Wab, Wsb, Imem, Iampa, Ishunt, Refr,
        pIdc, pIwa, pIws, pAlpha, pBeta,
        (float*)d_out, i0pow, kexp, tau_mem, inv_tau_syn);
}

// Round 6
// 385.099 us; speedup vs baseline: 1.0997x; 1.0582x over previous
//
#include <hip/hip_runtime.h>
#include <cmath>

#ifndef __has_builtin
#define __has_builtin(x) 0
#endif

#define B_DIM 4096
#define K_DIM 2048
#define N_DIM 2048

#define BM 128
#define BN 64
#define BK 64

typedef __attribute__((ext_vector_type(4))) float f32x4;
typedef __attribute__((ext_vector_type(8))) short bf16x8;
typedef __attribute__((ext_vector_type(8))) unsigned short u16x8;

// ---------- helpers ----------

__device__ __forceinline__ unsigned short f2bf(float f) {
    unsigned int u = __float_as_uint(f);
    u += 0x7fffu + ((u >> 16) & 1u);   // RNE; values here are small exact ints, no NaN
    return (unsigned short)(u >> 16);
}

__device__ __forceinline__ void gl2lds16(const void* g, void* l) {
#if __has_builtin(__builtin_amdgcn_global_load_lds)
    __builtin_amdgcn_global_load_lds((__attribute__((address_space(1))) void*)g,
                                     (__attribute__((address_space(3))) void*)l,
                                     16, 0, 0);
#else
    *(uint4*)l = *(const uint4*)g;
#endif
}

// ---------- prep: fused fp32 -> bf16 cast (X and both W in one launch) ----------

__global__ void cast_all_kernel(const float* __restrict__ X,
                                const float* __restrict__ Wa,
                                const float* __restrict__ Ws,
                                unsigned short* __restrict__ Xb,
                                unsigned short* __restrict__ Wab,
                                unsigned short* __restrict__ Wsb) {
    const int b = blockIdx.x;
    if (b < 4096) {                       // X: 8.39M elems, 2048/block
        size_t i = ((size_t)b * 256 + threadIdx.x) * 8;
        f32x4 a = *(const f32x4*)(X + i);
        f32x4 c = *(const f32x4*)(X + i + 4);
        u16x8 o;
        o[0] = f2bf(a[0]); o[1] = f2bf(a[1]); o[2] = f2bf(a[2]); o[3] = f2bf(a[3]);
        o[4] = f2bf(c[0]); o[5] = f2bf(c[1]); o[6] = f2bf(c[2]); o[7] = f2bf(c[3]);
        *(u16x8*)(Xb + i) = o;
    } else {                              // W: 4.19M elems each, 2048/block
        size_t i = ((size_t)(b - 4096) * 256 + threadIdx.x) * 8;
        f32x4 a0 = *(const f32x4*)(Wa + i);
        f32x4 a1 = *(const f32x4*)(Wa + i + 4);
        f32x4 s0 = *(const f32x4*)(Ws + i);
        f32x4 s1 = *(const f32x4*)(Ws + i + 4);
        u16x8 oa, os;
#pragma unroll
        for (int j = 0; j < 4; j++) {
            oa[j]     = f2bf(rintf(a0[j]));  // ste_round fwd = round-half-even
            oa[j + 4] = f2bf(rintf(a1[j]));
            os[j]     = f2bf(rintf(s0[j]));
            os[j + 4] = f2bf(rintf(s1[j]));
        }
        *(u16x8*)(Wab + i) = oa;
        *(u16x8*)(Wsb + i) = os;
    }
}

// ---------- fused dual-GEMM + DPI neuron update ----------
// 128x64 tile, BK=64, 4 waves 2x2 (wm in {0,64}, wn in {0,32}); each wave
// 64x32 via 4x2 mfma_f32_16x16x32_bf16 per GEMM. 34.8KB LDS -> 4 blocks/CU.
// XOR-swizzled staging keeps ds_read_b128 conflict-free. Epilogue transposes
// through ping-pong LDS buffers with register prefetch of the next s-step's
// state planes, so state loads overlap compute/stores (5 barriers, not 8).

#define RS 68    // LDS float row stride for epilogue (64 + 4 pad)

__global__ __launch_bounds__(256, 4)
void dpi_fused_kernel(const unsigned short* __restrict__ Xb,
                      const unsigned short* __restrict__ Wab,
                      const unsigned short* __restrict__ Wsb,
                      const float* __restrict__ gImem,
                      const float* __restrict__ gIampa,
                      const float* __restrict__ gIshunt,
                      const float* __restrict__ gRefr,
                      const float* __restrict__ pIdc,
                      const float* __restrict__ pIwa,
                      const float* __restrict__ pIws,
                      const float* __restrict__ pAlpha,
                      const float* __restrict__ pBeta,
                      float* __restrict__ out,
                      float i0pow, float kexp, float tau_mem, float inv_tau_syn)
{
    __shared__ __align__(16) unsigned char smem[34816];
    unsigned short* sA  = (unsigned short*)smem;             // 128x64 bf16 = 16 KB
    unsigned short* sWa = (unsigned short*)(smem + 16384);   //  64x64 bf16 =  8 KB
    unsigned short* sWs = (unsigned short*)(smem + 24576);   //  8 KB
    // epilogue ping-pong transpose buffers (reuse same memory)
    float* nbuf[2][2];  // [parity][0]=na, [parity][1]=ns; each 32*RS*4 = 8704 B
    nbuf[0][0] = (float*)smem;
    nbuf[0][1] = (float*)(smem + 8704);
    nbuf[1][0] = (float*)(smem + 17408);
    nbuf[1][1] = (float*)(smem + 26112);

    const int tid  = threadIdx.x;
    const int lane = tid & 63;
    const int wave = tid >> 6;

    // XCD-aware swizzle: 8 XCDs, each owns an 8(m) x 16(n) block region
    const int lin = blockIdx.x;                  // 0..1023
    const int xcd = lin & 7;
    const int loc = lin >> 3;                    // 0..127
    const int mb  = (xcd & 3) * 8 + (loc & 7);   // 0..31
    const int nb  = (xcd >> 2) * 16 + (loc >> 3);// 0..31
    const int m0  = mb * BM;
    const int n0  = nb * BN;

    const int wm = (wave & 1) * 64;
    const int wn = (wave >> 1) * 32;

    f32x4 accA[4][2], accS[4][2];
#pragma unroll
    for (int i = 0; i < 4; i++)
#pragma unroll
        for (int j = 0; j < 2; j++) { accA[i][j] = (f32x4)0.0f; accS[i][j] = (f32x4)0.0f; }

    const int frow = lane & 15;           // m (or n) within a 16-frag
    const int kq   = lane >> 4;           // 0..3 -> k sub-offset kq*8
    const int swzr = frow & 7;            // XOR swizzle row component

    for (int k0 = 0; k0 < K_DIM; k0 += BK) {
        // stage A (1024 x 16B chunks) + Wa/Ws (512 each). LDS dst is forced
        // contiguous (base + lane*16); XOR-swizzle the GLOBAL source chunk so
        // row r's chunk j lands at slot j^(r&7).
#pragma unroll
        for (int j = 0; j < 4; j++) {
            int c    = j * 256 + tid;
            int row  = c >> 3;
            int jsrc = (c & 7) ^ (row & 7);
            gl2lds16(Xb + (size_t)(m0 + row) * K_DIM + k0 + jsrc * 8, sA + c * 8);
        }
#pragma unroll
        for (int j = 0; j < 2; j++) {
            int c    = j * 256 + tid;
            int row  = c >> 3;
            int jsrc = (c & 7) ^ (row & 7);
            size_t goffW = (size_t)(n0 + row) * K_DIM + k0 + jsrc * 8;
            gl2lds16(Wab + goffW, sWa + c * 8);
            gl2lds16(Wsb + goffW, sWs + c * 8);
        }
        __syncthreads();

#pragma unroll
        for (int kk = 0; kk < 2; kk++) {
            const int jb = kk * 4 + kq;        // 16B chunk index of this lane's k
            const int ko = (jb ^ swzr) * 8;
            bf16x8 af[4], ba[2], bs[2];
#pragma unroll
            for (int mi = 0; mi < 4; mi++)
                af[mi] = *(const bf16x8*)(sA + (wm + mi * 16 + frow) * 64 + ko);
#pragma unroll
            for (int ni = 0; ni < 2; ni++) {
                const int o = (wn + ni * 16 + frow) * 64 + ko;
                ba[ni] = *(const bf16x8*)(sWa + o);
                bs[ni] = *(const bf16x8*)(sWs + o);
            }
#pragma unroll
            for (int mi = 0; mi < 4; mi++)
#pragma unroll
                for (int ni = 0; ni < 2; ni++) {
                    accA[mi][ni] = __builtin_amdgcn_mfma_f32_16x16x32_bf16(af[mi], ba[ni], accA[mi][ni], 0, 0, 0);
                    accS[mi][ni] = __builtin_amdgcn_mfma_f32_16x16x32_bf16(af[mi], bs[ni], accS[mi][ni], 0, 0, 0);
                }
        }
        __syncthreads();
    }

    // ---- epilogue: pipelined transpose + state prefetch + contiguous I/O ----
    const float idc   = *pIdc;
    const float iwa   = *pIwa;
    const float iws   = *pIws;
    const float alpha = *pAlpha;
    const float beta  = *pBeta;

    const size_t plane = (size_t)B_DIM * N_DIM;
    float* __restrict__ oSpike = out;
    float* __restrict__ oImem  = out + plane;
    float* __restrict__ oIampa = out + 2 * plane;
    float* __restrict__ oIsh   = out + 3 * plane;
    float* __restrict__ oRefr  = out + 4 * plane;

    const int rowgroup = wm >> 6;          // 0 or 1
    const int quad4    = (lane >> 4) << 2; // 0,4,8,12
    const int lcolb    = wn + (lane & 15); // scatter column base
    const int cseg     = (tid & 15) * 4;   // float4 column (0..60)
    const int rgrp     = tid >> 4;         // 0..15 -> rows rgrp*2..+1

    // global index for (s-step, q) of this thread
    auto gidx = [&](int s, int q) -> size_t {
        const int lrow = rgrp * 2 + q;
        const int grow = m0 + (lrow >> 4) * 64 + s * 16 + (lrow & 15);
        return (size_t)grow * N_DIM + n0 + cseg;
    };

    // prefetch state for s=0
    f32x4 pf_im[2], pf_ia[2], pf_is[2], pf_rf[2];
#pragma unroll
    for (int q = 0; q < 2; q++) {
        const size_t idx = gidx(0, q);
        pf_im[q] = *(const f32x4*)(gImem   + idx);
        pf_ia[q] = *(const f32x4*)(gIampa  + idx);
        pf_is[q] = *(const f32x4*)(gIshunt + idx);
        pf_rf[q] = *(const f32x4*)(gRefr   + idx);
    }

    // scatter s=0 fragments into buf parity 0
#pragma unroll
    for (int ni = 0; ni < 2; ni++) {
        const int lcol = lcolb + ni * 16;
#pragma unroll
        for (int r = 0; r < 4; r++) {
            const int lrow = rowgroup * 16 + quad4 + r;
            nbuf[0][0][lrow * RS + lcol] = accA[0][ni][r];
            nbuf[0][1][lrow * RS + lcol] = accS[0][ni][r];
        }
    }
    __syncthreads();

#pragma unroll
    for (int s = 0; s < 4; s++) {
        const int cur = s & 1;
        float* na_c = nbuf[cur][0];
        float* ns_c = nbuf[cur][1];

        // consume prefetched state into locals
        f32x4 im4[2], ia4[2], is4[2], rf4[2];
#pragma unroll
        for (int q = 0; q < 2; q++) {
            im4[q] = pf_im[q]; ia4[q] = pf_ia[q];
            is4[q] = pf_is[q]; rf4[q] = pf_rf[q];
        }
        // issue prefetch for s+1 (overlaps with compute + stores below)
        if (s < 3) {
#pragma unroll
            for (int q = 0; q < 2; q++) {
                const size_t idx = gidx(s + 1, q);
                pf_im[q] = *(const f32x4*)(gImem   + idx);
                pf_ia[q] = *(const f32x4*)(gIampa  + idx);
                pf_is[q] = *(const f32x4*)(gIshunt + idx);
                pf_rf[q] = *(const f32x4*)(gRefr   + idx);
            }
        }

        // compute + store current step
#pragma unroll
        for (int q = 0; q < 2; q++) {
            const int lrow = rgrp * 2 + q;
            const size_t idx = gidx(s, q);
            const f32x4 na4 = *(const f32x4*)(na_c + lrow * RS + cseg);
            const f32x4 ns4 = *(const f32x4*)(ns_c + lrow * RS + cseg);

            f32x4 sp_o, im_o, ia_o, is_o, rf_o;
#pragma unroll
            for (int e = 0; e < 4; e++) {
                const float na  = na4[e];
                const float ns  = ns4[e];
                const float im  = im4[q][e];
                const float ia  = ia4[q][e];
                const float ish = is4[q][e];
                const float rf  = rf4[q][e];

                const float dIampa  = -ia * inv_tau_syn;
                const float ia2     = ia + iwa * na;        // IGAIN_AMPA/ITAU_AMPA = 1
                const float dIshunt = -ish * inv_tau_syn;   // TAU_SHUNT == TAU_AMPA
                const float ish2    = ish + iws * ns;

                float Iin = idc + ia2 + 5e-13f - ish2;      // Inmda = I0
                Iin = (rf <= 0.0f) ? Iin : 0.0f;
                Iin = fmaxf(Iin, 5e-13f);

                // 1+exp(-1e-12*(im-1e-12)): |arg| < 1e-21 -> exp == 1.0f exactly
                // in fp32, denominator == 2.0f. powf via v_log/v_exp.
                const float ifb = i0pow *
                    __builtin_amdgcn_exp2f(kexp * __builtin_amdgcn_logf(im)) * 0.5f;
                const float fimem = ifb * 1e12f * (im + 1e-12f);
                const float dImem = (alpha * ((Iin - 1e-12f) - 5e-13f) - beta * im + fimem)
                                    / (tau_mem * (1.0f + 1e-12f / im));
                float im2 = fmaxf(im + dImem * 0.001f, 5e-13f);

                float ia3 = fmaxf(ia2 + dIampa * 0.001f, 5e-13f);
                ia3       = fmaxf(ia3 + dIshunt * 0.001f, 5e-13f);  // faithful to ref bug

                const float spike = (im2 - 1e-12f > 0.0f) ? 1.0f : 0.0f;
                im2 = (spike > 0.0f) ? 5e-13f : im2;
                float rf2 = fmaxf(rf - 0.001f, 0.0f);
                rf2 = (spike > 0.0f) ? 0.0f : rf2;          // REFP = 0

                sp_o[e] = spike; im_o[e] = im2; ia_o[e] = ia3;
                is_o[e] = ish2;  rf_o[e] = rf2;
            }

            *(f32x4*)(oSpike + idx) = sp_o;
            *(f32x4*)(oImem  + idx) = im_o;
            *(f32x4*)(oIampa + idx) = ia_o;
            *(f32x4*)(oIsh   + idx) = is_o;
            *(f32x4*)(oRefr  + idx) = rf_o;
        }

        // scatter next step's fragments into the other buffer
        if (s < 3) {
            float* na_n = nbuf[1 - cur][0];
            float* ns_n = nbuf[1 - cur][1];
#pragma unroll
            for (int ni = 0; ni < 2; ni++) {
                const int lcol = lcolb + ni * 16;
#pragma unroll
                for (int r = 0; r < 4; r++) {
                    const int lrow = rowgroup * 16 + quad4 + r;
                    na_n[lrow * RS + lcol] = accA[s + 1][ni][r];
                    ns_n[lrow * RS + lcol] = accS[s + 1][ni][r];
                }
            }
        }
        __syncthreads();
    }
}

// ---------- launch ----------

extern "C" void kernel_launch(void* const* d_in, const int* in_sizes, int n_in,
                              void* d_out, int out_size, void* d_ws, size_t ws_size,
                              hipStream_t stream) {
    (void)in_sizes; (void)n_in; (void)out_size; (void)ws_size;

    const float* X       = (const float*)d_in[0];
    const float* W_ampa  = (const float*)d_in[1];
    const float* W_shunt = (const float*)d_in[2];
    const float* Imem    = (const float*)d_in[3];
    const float* Iampa   = (const float*)d_in[4];
    const float* Ishunt  = (const float*)d_in[5];
    const float* Refr    = (const float*)d_in[6];
    const float* pIdc    = (const float*)d_in[7];
    const float* pIwa    = (const float*)d_in[8];
    const float* pIws    = (const float*)d_in[9];
    const float* pAlpha  = (const float*)d_in[10];
    const float* pBeta   = (const float*)d_in[11];

    unsigned short* Xb  = (unsigned short*)d_ws;                 // 16 MiB
    unsigned short* Wab = Xb  + (size_t)B_DIM * K_DIM;           // 8 MiB
    unsigned short* Wsb = Wab + (size_t)N_DIM * K_DIM;           // 8 MiB

    const float i0pow       = (float)std::pow(5e-13, 1.0 / 1.705);   // I0^(1/(k+1))
    const float kexp        = (float)(0.705 / 1.705);                // k/(k+1)
    const float tau_mem     = (float)(0.025 / 0.705 * 3.0);
    const float inv_tau_syn = (float)(1.0 / (0.025 / 0.705 * 2.0));

    cast_all_kernel<<<dim3(6144), dim3(256), 0, stream>>>(
        X, W_ampa, W_shunt, Xb, Wab, Wsb);

    dpi_fused_kernel<<<dim3((B_DIM / BM) * (N_DIM / BN)), dim3(256), 0, stream>>>(
        Xb, Wab, Wsb, Imem, Iampa, Ishunt, Refr,
        pIdc, pIwa, pIws, pAlpha, pBeta,
        (float*)d_out, i0pow, kexp, tau_mem, inv_tau_syn);
}